// Round 7
// baseline (180.489 us; speedup 1.0000x reference)
//
#include <hip/hip_runtime.h>

// LinearAttention, bf16 MFMA pipeline (R7: ctx fused into gemm_qkv epilogue).
// x:(16,256,64,64) fp32, w_qkv:(768,256), w_out:(256,256), b_out:(256), gamma/beta:(256)
// N=4096, HEADS=8, DIM_HEAD=32, groups=32.
//
// gemm_qkv M-tiling: y=0,1 -> q rows (softmax-d epilogue -> qT);
// y=2+r (r=0..3) -> k rows [256+64r,+64) as local 0..63 AND v rows [512+64r,+64)
// as local 64..127 (same head pair 2r,2r+1). Epilogue computes
// ctx[d][e] += sum_n exp(k[d][n]) v[e][n] in-block via MFMA, atomicAdd to ctxp;
// k/v never touch HBM.

typedef short s8v __attribute__((ext_vector_type(8)));
typedef float f32x4 __attribute__((ext_vector_type(4)));

__device__ __forceinline__ short f2bf(float f) {
  union { float f; unsigned u; } v; v.f = f;
  unsigned r = v.u + 0x7FFF + ((v.u >> 16) & 1);
  return (short)(r >> 16);
}
__device__ __forceinline__ float bf2f(short h) {
  union { unsigned u; float f; } v; v.u = ((unsigned)(unsigned short)h) << 16;
  return v.f;
}
__device__ __forceinline__ void gld16(const short* g, short* l) {
  __builtin_amdgcn_global_load_lds(
      (const __attribute__((address_space(1))) unsigned*)g,
      (__attribute__((address_space(3))) unsigned*)l, 16, 0, 0);
}

// ---------------- w_qkv cast + zero accumulators (ctxp|sp|st2, contiguous) ----
__global__ __launch_bounds__(256) void cast_w(
    const float* __restrict__ src, short* __restrict__ dst, float* __restrict__ zbase) {
  int bx = blockIdx.x;
  if (bx >= 96) {
    int idx = (bx - 96) * 256 + threadIdx.x;  // 34048 float4 = 136192 floats
    float4 z = {0.f, 0.f, 0.f, 0.f};
    ((float4*)zbase)[idx] = z;
    return;
  }
  int id = bx * 256 + threadIdx.x;
  long off = (long)id * 8;
  float4 a = *(const float4*)&src[off];
  float4 b = *(const float4*)&src[off + 4];
  s8v o;
  o[0] = f2bf(a.x); o[1] = f2bf(a.y); o[2] = f2bf(a.z); o[3] = f2bf(a.w);
  o[4] = f2bf(b.x); o[5] = f2bf(b.y); o[6] = f2bf(b.z); o[7] = f2bf(b.w);
  *(s8v*)&dst[off] = o;
}

// ---------------- x[b][c][n] fp32 -> xt[b][n][c] bf16 -------------------------
__global__ __launch_bounds__(256) void cast_transpose_x(
    const float* __restrict__ x, short* __restrict__ xt) {
  int b = blockIdx.z;
  int n0 = blockIdx.x * 64, c0 = blockIdx.y * 64;
  __shared__ short ls[64][65];  // [n_local][c_local]
  int t = threadIdx.x;
  const float* xb = x + ((long)b * 256 + c0) * 4096 + n0;
  int ci = t >> 4, j4 = (t & 15) * 4;
#pragma unroll
  for (int i = 0; i < 4; ++i) {
    int cl = ci + i * 16;
    float4 v = *(const float4*)&xb[(long)cl * 4096 + j4];
    ls[j4 + 0][cl] = f2bf(v.x);
    ls[j4 + 1][cl] = f2bf(v.y);
    ls[j4 + 2][cl] = f2bf(v.z);
    ls[j4 + 3][cl] = f2bf(v.w);
  }
  __syncthreads();
  short* xtb = xt + ((long)b * 4096 + n0) * 256 + c0;
#pragma unroll
  for (int i = 0; i < 2; ++i) {
    int id = t + i * 256;
    int nl = id >> 3, c8 = (id & 7) * 8;
    s8v o;
#pragma unroll
    for (int e = 0; e < 8; ++e) o[e] = ls[nl][c8 + e];
    *(s8v*)&xtb[(long)nl * 256 + c8] = o;
  }
}

// ---------------- GEMM1: qkv + fused q-softmax/qT + fused ctx ------------------
__global__ __launch_bounds__(256) void gemm_qkv(
    const short* __restrict__ A, const short* __restrict__ Bt,
    short* __restrict__ qT, float* __restrict__ ctxp, float* __restrict__ sp) {
  __shared__ short smem[16384];
  short* lA = smem;
  short* lB = smem + 8192;
  int b = blockIdx.z;
  int mt = blockIdx.y * 128, nt = blockIdx.x * 128;
  bool isq = mt < 256;
  int r = (mt - 256) >> 7;       // 0..3 for kv blocks
  int kbase = 256 + r * 64;      // global A-row of local row 0 (k part)
  int tid = threadIdx.x;
  int lane = tid & 63;
  int wm = tid >> 7, wn = (tid >> 6) & 1;
  int rl = lane & 15, kg = lane >> 4;
  const short* Bb = Bt + ((long)b * 4096 + nt) * 256;

  f32x4 acc[4][4];
#pragma unroll
  for (int i = 0; i < 4; ++i)
#pragma unroll
    for (int j = 0; j < 4; ++j) acc[i][j] = (f32x4){0.f, 0.f, 0.f, 0.f};

  for (int k0 = 0; k0 < 256; k0 += 64) {
#pragma unroll
    for (int is = 0; is < 4; ++is) {
      int s = is * 256 + tid;
      int row = s >> 3, kcp = s & 7;
      int kcl = kcp ^ (row & 7);
      int grow = isq ? (mt + row) : (kbase + row + ((row >= 64) ? 192 : 0));
      gld16(A + (long)grow * 256 + k0 + kcl * 8, &lA[(is * 256 + (tid & ~63)) * 8]);
      gld16(Bb + (long)row * 256 + k0 + kcl * 8, &lB[(is * 256 + (tid & ~63)) * 8]);
    }
    asm volatile("s_waitcnt vmcnt(0)" ::: "memory");
    __syncthreads();
#pragma unroll
    for (int kw = 0; kw < 2; ++kw) {
      int kc = kw * 4 + kg;
      s8v av[4], bv[4];
#pragma unroll
      for (int mi = 0; mi < 4; ++mi) {
        int row = wm * 64 + mi * 16 + rl;
        av[mi] = *(const s8v*)&lA[row * 64 + ((kc ^ (row & 7)) << 3)];
      }
#pragma unroll
      for (int ni = 0; ni < 4; ++ni) {
        int row = wn * 64 + ni * 16 + rl;
        bv[ni] = *(const s8v*)&lB[row * 64 + ((kc ^ (row & 7)) << 3)];
      }
#pragma unroll
      for (int mi = 0; mi < 4; ++mi)
#pragma unroll
        for (int ni = 0; ni < 4; ++ni)
          acc[mi][ni] = __builtin_amdgcn_mfma_f32_16x16x32_bf16(
              av[mi], bv[ni], acc[mi][ni], 0, 0, 0);
    }
    __syncthreads();
  }

  if (isq) {
    // q tiles: softmax over d (32 channels/head), write qT[b][n][c]
    short* qTb = qT + ((long)b * 4096 + nt) * 256 + mt;
#pragma unroll
    for (int ni = 0; ni < 4; ++ni) {
      int n = wn * 64 + ni * 16 + rl;
#pragma unroll
      for (int p = 0; p < 2; ++p) {
        float v[8];
        float m = -1e30f;
#pragma unroll
        for (int j = 0; j < 8; ++j) {
          v[j] = acc[p * 2 + (j >> 2)][ni][j & 3];
          m = fmaxf(m, v[j]);
        }
        m = fmaxf(m, __shfl_xor(m, 16));
        m = fmaxf(m, __shfl_xor(m, 32));
        float ssum = 0.f;
#pragma unroll
        for (int j = 0; j < 8; ++j) { v[j] = __expf(v[j] - m); ssum += v[j]; }
        ssum += __shfl_xor(ssum, 16);
        ssum += __shfl_xor(ssum, 32);
        float inv = 1.f / ssum;
#pragma unroll
        for (int half = 0; half < 2; ++half) {
          short4 o;
          o.x = f2bf(v[half * 4 + 0] * inv);
          o.y = f2bf(v[half * 4 + 1] * inv);
          o.z = f2bf(v[half * 4 + 2] * inv);
          o.w = f2bf(v[half * 4 + 3] * inv);
          *(short4*)&qTb[(long)n * 256 + wm * 64 + p * 32 + half * 16 + kg * 4] = o;
        }
      }
    }
  } else {
    // kv tiles: exp(k) + denominator, stash exp(k)/v in LDS, ctx MFMA, atomics.
    int h2 = 2 * r;
    // 1) write tiles to LDS as [kv(0/1)][64 rows][128 cols] bf16, XOR-swizzled
    //    on 8-elem chunks; k-waves apply exp and accumulate row sums.
#pragma unroll
    for (int mi = 0; mi < 4; ++mi) {
#pragma unroll
      for (int rr = 0; rr < 4; ++rr) {
        int rowl = mi * 16 + kg * 4 + rr;  // 0..63
        float rs = 0.f;
#pragma unroll
        for (int ni = 0; ni < 4; ++ni) {
          int col = wn * 64 + ni * 16 + rl;  // 0..127
          float val = acc[mi][ni][rr];
          if (wm == 0) { val = __expf(val); rs += val; }
          int phys = (((col >> 3) ^ (rowl & 7)) << 3) | (col & 7);
          smem[(wm * 64 + rowl) * 128 + phys] = f2bf(val);
        }
        if (wm == 0) {
          rs += __shfl_xor(rs, 1); rs += __shfl_xor(rs, 2);
          rs += __shfl_xor(rs, 4); rs += __shfl_xor(rs, 8);
          if (rl == 0)
            atomicAdd(&sp[((long)b * 8 + h2 + (rowl >> 5)) * 32 + (rowl & 31)], rs);
        }
      }
    }
    __syncthreads();
    // 2) ctx MFMA: wave w -> head hh=w&1, n-half nh=w>>1; 32x32 over K=64.
    int w = tid >> 6;
    int hh = w & 1, nh = w >> 1;
    f32x4 c2[2][2];
#pragma unroll
    for (int i = 0; i < 2; ++i)
#pragma unroll
      for (int j = 0; j < 2; ++j) c2[i][j] = (f32x4){0.f, 0.f, 0.f, 0.f};
#pragma unroll
    for (int ks = 0; ks < 2; ++ks) {
      int col = nh * 64 + ks * 32 + kg * 8;
      int chunk = col >> 3;
      s8v ka[2], va[2];
#pragma unroll
      for (int mi = 0; mi < 2; ++mi) {
        int rowk = hh * 32 + mi * 16 + rl;        // 0..63
        int rowv = 64 + hh * 32 + mi * 16 + rl;   // 64..127
        ka[mi] = *(const s8v*)&smem[rowk * 128 + ((chunk ^ (rowk & 7)) << 3)];
        va[mi] = *(const s8v*)&smem[rowv * 128 + ((chunk ^ (rowv & 7)) << 3)];
      }
#pragma unroll
      for (int di = 0; di < 2; ++di)
#pragma unroll
        for (int ei = 0; ei < 2; ++ei)
          c2[di][ei] = __builtin_amdgcn_mfma_f32_16x16x32_bf16(
              ka[di], va[ei], c2[di][ei], 0, 0, 0);
    }
    // 3) atomic accumulate into ctxp[b][h][d*32+e]
    float* cbase = ctxp + ((long)b * 8 + h2 + hh) * 1024;
#pragma unroll
    for (int di = 0; di < 2; ++di)
#pragma unroll
      for (int ei = 0; ei < 2; ++ei)
#pragma unroll
        for (int rr = 0; rr < 4; ++rr) {
          int d = di * 16 + kg * 4 + rr;
          int e = ei * 16 + rl;
          atomicAdd(&cbase[d * 32 + e], c2[di][ei][rr]);
        }
  }
}

// ---------------- GEMM2: lin = Wf[b] @ qT^T + b_out, fused GN partial stats ---
__global__ __launch_bounds__(256) void gemm_lin(
    const short* __restrict__ A, const short* __restrict__ Bt,
    short* __restrict__ C, const float* __restrict__ bias,
    float* __restrict__ st2) {
  __shared__ short lA[8192];
  __shared__ short lB[8192];
  int b = blockIdx.z;
  int mt = blockIdx.y * 128, nt = blockIdx.x * 128;
  int tid = threadIdx.x;
  int lane = tid & 63;
  int wm = tid >> 7, wn = (tid >> 6) & 1;
  int rl = lane & 15, kg = lane >> 4;
  const short* Ab = A + (long)b * 65536 + (long)mt * 256;
  const short* Bb = Bt + ((long)b * 4096 + nt) * 256;

  f32x4 acc[4][4];
#pragma unroll
  for (int i = 0; i < 4; ++i)
#pragma unroll
    for (int j = 0; j < 4; ++j) acc[i][j] = (f32x4){0.f, 0.f, 0.f, 0.f};

  for (int k0 = 0; k0 < 256; k0 += 64) {
#pragma unroll
    for (int is = 0; is < 4; ++is) {
      int s = is * 256 + tid;
      int row = s >> 3, kcp = s & 7;
      int kcl = kcp ^ (row & 7);
      gld16(Ab + (long)row * 256 + k0 + kcl * 8, &lA[(is * 256 + (tid & ~63)) * 8]);
      gld16(Bb + (long)row * 256 + k0 + kcl * 8, &lB[(is * 256 + (tid & ~63)) * 8]);
    }
    asm volatile("s_waitcnt vmcnt(0)" ::: "memory");
    __syncthreads();
#pragma unroll
    for (int kw = 0; kw < 2; ++kw) {
      int kc = kw * 4 + kg;
      s8v av[4], bv[4];
#pragma unroll
      for (int mi = 0; mi < 4; ++mi) {
        int row = wm * 64 + mi * 16 + rl;
        av[mi] = *(const s8v*)&lA[row * 64 + ((kc ^ (row & 7)) << 3)];
      }
#pragma unroll
      for (int ni = 0; ni < 4; ++ni) {
        int row = wn * 64 + ni * 16 + rl;
        bv[ni] = *(const s8v*)&lB[row * 64 + ((kc ^ (row & 7)) << 3)];
      }
#pragma unroll
      for (int mi = 0; mi < 4; ++mi)
#pragma unroll
        for (int ni = 0; ni < 4; ++ni)
          acc[mi][ni] = __builtin_amdgcn_mfma_f32_16x16x32_bf16(
              av[mi], bv[ni], acc[mi][ni], 0, 0, 0);
    }
    __syncthreads();
  }

  short* Cb = C + ((long)b * 256 + mt) * 4096 + nt;
  float s1[4] = {0.f, 0.f, 0.f, 0.f};
  float s2[4] = {0.f, 0.f, 0.f, 0.f};
#pragma unroll
  for (int mi = 0; mi < 4; ++mi) {
#pragma unroll
    for (int r = 0; r < 4; ++r) {
      int o = wm * 64 + mi * 16 + kg * 4 + r;
      float bv = bias[mt + o];
#pragma unroll
      for (int ni = 0; ni < 4; ++ni) {
        int n = wn * 64 + ni * 16 + rl;
        short h = f2bf(acc[mi][ni][r] + bv);
        Cb[(long)o * 4096 + n] = h;
        float q = bf2f(h);
        s1[mi] += q;
        s2[mi] += q * q;
      }
    }
  }
#pragma unroll
  for (int mi = 0; mi < 4; ++mi) {
#pragma unroll
    for (int off = 1; off <= 16; off <<= 1) {
      s1[mi] += __shfl_xor(s1[mi], off);
      s2[mi] += __shfl_xor(s2[mi], off);
    }
    if (rl == 0 && (kg & 1) == 0) {
      int g = (mt >> 3) + wm * 8 + mi * 2 + (kg >> 1);
      atomicAdd(&st2[(b * 32 + g) * 2], s1[mi]);
      atomicAdd(&st2[(b * 32 + g) * 2 + 1], s2[mi]);
    }
  }
}

// ---------------- Wf[b][o][h*32+d] = sum_e w_out[o][h*32+e] * ctx[d][e]/s_d ---
__global__ __launch_bounds__(256) void make_wf(
    const float* __restrict__ ctxp, const float* __restrict__ sp,
    const float* __restrict__ w_out, short* __restrict__ wf) {
  int h = blockIdx.x, b = blockIdx.y;
  __shared__ float c[32][33];
  __shared__ float inv_s[32];
  __shared__ float wv[256][33];
  int t = threadIdx.x;
  long base = (long)(b * 8 + h);
#pragma unroll
  for (int i = 0; i < 4; ++i) {
    int id = t + i * 256;
    c[id >> 5][id & 31] = ctxp[base * 1024 + id];
  }
  if (t < 32) inv_s[t] = 1.f / sp[base * 32 + t];
#pragma unroll
  for (int r = 0; r < 32; ++r) {
    int row = r * 8 + (t >> 5);
    wv[row][t & 31] = w_out[row * 256 + h * 32 + (t & 31)];
  }
  __syncthreads();
  float wr[32];
#pragma unroll
  for (int e = 0; e < 32; ++e) wr[e] = wv[t][e];
  float tmp[32];
#pragma unroll
  for (int dd = 0; dd < 32; ++dd) {
    float sum = 0.f;
#pragma unroll
    for (int e = 0; e < 32; ++e) sum += wr[e] * c[dd][e];
    tmp[dd] = sum * inv_s[dd];
  }
  short* dst = wf + ((long)b * 256 + t) * 256 + h * 32;
#pragma unroll
  for (int c8 = 0; c8 < 4; ++c8) {
    s8v o;
#pragma unroll
    for (int e = 0; e < 8; ++e) o[e] = f2bf(tmp[c8 * 8 + e]);
    *(s8v*)&dst[c8 * 8] = o;
  }
}

// ---------------- normalize + affine + residual --------------------------------
__global__ __launch_bounds__(256) void final_out(
    const short* __restrict__ lin, const float* __restrict__ x,
    const float2* __restrict__ st2, const float* __restrict__ gamma,
    const float* __restrict__ beta, float* __restrict__ out) {
  long id = (long)blockIdx.x * 256 + threadIdx.x;
  long e0 = id * 8;
  int b = (int)(e0 >> 20);
  int rem = (int)(e0 & 1048575);
  int c = rem >> 12;
  float2 st = st2[b * 32 + (c >> 3)];
  float mean = st.x * (1.f / 32768.f);
  float inv = rsqrtf(st.y * (1.f / 32768.f) - mean * mean + 1e-6f);
  float ga = gamma[c] * inv;
  float be = beta[c] - mean * ga;
  s8v l8 = *(const s8v*)&lin[e0];
  float4 x0 = *(const float4*)&x[e0];
  float4 x1 = *(const float4*)&x[e0 + 4];
  float4 o0, o1;
  o0.x = bf2f(l8[0]) * ga + be + x0.x;
  o0.y = bf2f(l8[1]) * ga + be + x0.y;
  o0.z = bf2f(l8[2]) * ga + be + x0.z;
  o0.w = bf2f(l8[3]) * ga + be + x0.w;
  o1.x = bf2f(l8[4]) * ga + be + x1.x;
  o1.y = bf2f(l8[5]) * ga + be + x1.y;
  o1.z = bf2f(l8[6]) * ga + be + x1.z;
  o1.w = bf2f(l8[7]) * ga + be + x1.w;
  *(float4*)&out[e0] = o0;
  *(float4*)&out[e0 + 4] = o1;
}

extern "C" void kernel_launch(void* const* d_in, const int* in_sizes, int n_in,
                              void* d_out, int out_size, void* d_ws, size_t ws_size,
                              hipStream_t stream) {
  const float* x     = (const float*)d_in[0];
  const float* w_qkv = (const float*)d_in[1];
  const float* w_out = (const float*)d_in[2];
  const float* b_out = (const float*)d_in[3];
  const float* gamma = (const float*)d_in[4];
  const float* beta  = (const float*)d_in[5];
  float* out = (float*)d_out;

  short* xt   = (short*)d_ws;              // 16*4096*256 shorts (32MB)
  short* qT   = xt + 16777216;             // 32MB
  short* lin  = qT + 16777216;             // 32MB
  short* wqb  = lin + 16777216;            // 196,608 shorts
  short* wfb  = wqb + 196608;              // 1M shorts
  float* ctxp = (float*)(wfb + 1048576);   // 131,072 floats  (zero region start)
  float* sp   = ctxp + 131072;             // 4,096 floats
  float* st2  = sp + 4096;                 // 1,024 floats

  cast_w<<<229, 256, 0, stream>>>(w_qkv, wqb, ctxp);
  cast_transpose_x<<<dim3(64, 4, 16), 256, 0, stream>>>(x, xt);
  gemm_qkv<<<dim3(32, 6, 16), 256, 0, stream>>>(wqb, xt, qT, ctxp, sp);
  make_wf<<<dim3(8, 16), 256, 0, stream>>>(ctxp, sp, w_out, wfb);
  gemm_lin<<<dim3(32, 2, 16), 256, 0, stream>>>(wfb, qT, lin, b_out, st2);
  final_out<<<8192, 256, 0, stream>>>(lin, x, (const float2*)st2, gamma, beta, out);
}

// Round 9
// 145.425 us; speedup vs baseline: 1.2411x; 1.2411x over previous
//
#include <hip/hip_runtime.h>

// LinearAttention, bf16 MFMA pipeline (R9: R8 with st2-zeroing fixed).
// x:(16,256,64,64) fp32, w_qkv:(768,256), w_out:(256,256), b_out:(256), gamma/beta:(256)
// N=4096, HEADS=8, DIM_HEAD=32, groups=32.

typedef short s8v __attribute__((ext_vector_type(8)));
typedef float f32x4 __attribute__((ext_vector_type(4)));

__device__ __forceinline__ short f2bf(float f) {          // round-to-nearest-even-ish
  union { float f; unsigned u; } v; v.f = f;
  unsigned r = v.u + 0x7FFF + ((v.u >> 16) & 1);
  return (short)(r >> 16);
}
__device__ __forceinline__ short f2bf_t(float f) {        // truncate (1 op)
  union { float f; unsigned u; } v; v.f = f;
  return (short)(v.u >> 16);
}
__device__ __forceinline__ float bf2f(short h) {
  union { unsigned u; float f; } v; v.u = ((unsigned)(unsigned short)h) << 16;
  return v.f;
}
__device__ __forceinline__ void gld16(const short* g, short* l) {
  __builtin_amdgcn_global_load_lds(
      (const __attribute__((address_space(1))) unsigned*)g,
      (__attribute__((address_space(3))) unsigned*)l, 16, 0, 0);
}

// ---------------- prep: x transpose+cast, w_qkv cast, zero st2 -----------------
// z<16: x[b][c][n] fp32 -> xt[b][n][c] bf16.  z==16: slot<96 cast w_qkv,
// slot==96 zero st2 (1024 floats -- the ONLY buffer that accumulates atomics).
__global__ __launch_bounds__(256) void prep(
    const float* __restrict__ x, short* __restrict__ xt,
    const float* __restrict__ wsrc, short* __restrict__ wdst,
    float* __restrict__ st2) {
  int t = threadIdx.x;
  if (blockIdx.z == 16) {
    int slot = blockIdx.y * 64 + blockIdx.x;
    if (slot < 96) {
      int id = slot * 256 + t;
      long off = (long)id * 8;
      float4 a = *(const float4*)&wsrc[off];
      float4 b = *(const float4*)&wsrc[off + 4];
      s8v o;
      o[0] = f2bf(a.x); o[1] = f2bf(a.y); o[2] = f2bf(a.z); o[3] = f2bf(a.w);
      o[4] = f2bf(b.x); o[5] = f2bf(b.y); o[6] = f2bf(b.z); o[7] = f2bf(b.w);
      *(s8v*)&wdst[off] = o;
    } else if (slot == 96) {
      float4 z = {0.f, 0.f, 0.f, 0.f};
      ((float4*)st2)[t] = z;  // 1024 floats
    }
    return;
  }
  int b = blockIdx.z;
  int n0 = blockIdx.x * 64, c0 = blockIdx.y * 64;
  __shared__ short ls[64][65];  // [n_local][c_local]
  const float* xb = x + ((long)b * 256 + c0) * 4096 + n0;
  int ci = t >> 4, j4 = (t & 15) * 4;
#pragma unroll
  for (int i = 0; i < 4; ++i) {
    int cl = ci + i * 16;
    float4 v = *(const float4*)&xb[(long)cl * 4096 + j4];
    ls[j4 + 0][cl] = f2bf(v.x);
    ls[j4 + 1][cl] = f2bf(v.y);
    ls[j4 + 2][cl] = f2bf(v.z);
    ls[j4 + 3][cl] = f2bf(v.w);
  }
  __syncthreads();
  short* xtb = xt + ((long)b * 4096 + n0) * 256 + c0;
#pragma unroll
  for (int i = 0; i < 2; ++i) {
    int id = t + i * 256;
    int nl = id >> 3, c8 = (id & 7) * 8;
    s8v o;
#pragma unroll
    for (int e = 0; e < 8; ++e) o[e] = ls[nl][c8 + e];
    *(s8v*)&xtb[(long)nl * 256 + c8] = o;
  }
}

// ---------------- GEMM1: qkv = w_qkv @ x, fused q-softmax + qT write ----------
__global__ __launch_bounds__(256) void gemm_qkv(
    const short* __restrict__ A, const short* __restrict__ Bt,
    short* __restrict__ kv, short* __restrict__ qT) {
  __shared__ short lA[8192];
  __shared__ short lB[8192];
  int b = blockIdx.z;
  int mt = blockIdx.y * 128, nt = blockIdx.x * 128;
  int tid = threadIdx.x;
  int lane = tid & 63;
  int wm = tid >> 7, wn = (tid >> 6) & 1;
  int rl = lane & 15, kg = lane >> 4;
  const short* Ab = A + (long)mt * 256;
  const short* Bb = Bt + ((long)b * 4096 + nt) * 256;

  f32x4 acc[4][4];
#pragma unroll
  for (int i = 0; i < 4; ++i)
#pragma unroll
    for (int j = 0; j < 4; ++j) acc[i][j] = (f32x4){0.f, 0.f, 0.f, 0.f};

  for (int k0 = 0; k0 < 256; k0 += 64) {
#pragma unroll
    for (int is = 0; is < 4; ++is) {
      int s = is * 256 + tid;
      int row = s >> 3, kcp = s & 7;
      int kcl = kcp ^ (row & 7);
      gld16(Ab + (long)row * 256 + k0 + kcl * 8, &lA[(is * 256 + (tid & ~63)) * 8]);
      gld16(Bb + (long)row * 256 + k0 + kcl * 8, &lB[(is * 256 + (tid & ~63)) * 8]);
    }
    asm volatile("s_waitcnt vmcnt(0)" ::: "memory");
    __syncthreads();
#pragma unroll
    for (int kw = 0; kw < 2; ++kw) {
      int kc = kw * 4 + kg;
      s8v av[4], bv[4];
#pragma unroll
      for (int mi = 0; mi < 4; ++mi) {
        int row = wm * 64 + mi * 16 + rl;
        av[mi] = *(const s8v*)&lA[row * 64 + ((kc ^ (row & 7)) << 3)];
      }
#pragma unroll
      for (int ni = 0; ni < 4; ++ni) {
        int row = wn * 64 + ni * 16 + rl;
        bv[ni] = *(const s8v*)&lB[row * 64 + ((kc ^ (row & 7)) << 3)];
      }
#pragma unroll
      for (int mi = 0; mi < 4; ++mi)
#pragma unroll
        for (int ni = 0; ni < 4; ++ni)
          acc[mi][ni] = __builtin_amdgcn_mfma_f32_16x16x32_bf16(
              av[mi], bv[ni], acc[mi][ni], 0, 0, 0);
    }
    __syncthreads();
  }

  if (mt < 256) {
    // q tiles: softmax over d (32 channels/head), write qT[b][n][c]
    short* qTb = qT + ((long)b * 4096 + nt) * 256 + mt;
#pragma unroll
    for (int ni = 0; ni < 4; ++ni) {
      int n = wn * 64 + ni * 16 + rl;
#pragma unroll
      for (int p = 0; p < 2; ++p) {
        float v[8];
        float m = -1e30f;
#pragma unroll
        for (int j = 0; j < 8; ++j) {
          v[j] = acc[p * 2 + (j >> 2)][ni][j & 3];
          m = fmaxf(m, v[j]);
        }
        m = fmaxf(m, __shfl_xor(m, 16));
        m = fmaxf(m, __shfl_xor(m, 32));
        float ssum = 0.f;
#pragma unroll
        for (int j = 0; j < 8; ++j) { v[j] = __expf(v[j] - m); ssum += v[j]; }
        ssum += __shfl_xor(ssum, 16);
        ssum += __shfl_xor(ssum, 32);
        float inv = 1.f / ssum;
#pragma unroll
        for (int half = 0; half < 2; ++half) {
          short4 o;
          o.x = f2bf_t(v[half * 4 + 0] * inv);
          o.y = f2bf_t(v[half * 4 + 1] * inv);
          o.z = f2bf_t(v[half * 4 + 2] * inv);
          o.w = f2bf_t(v[half * 4 + 3] * inv);
          *(short4*)&qTb[(long)n * 256 + wm * 64 + p * 32 + half * 16 + kg * 4] = o;
        }
      }
    }
  } else {
    short* Cb = kv + ((long)b * 512 + (mt - 256)) * 4096 + nt;
#pragma unroll
    for (int mi = 0; mi < 4; ++mi) {
#pragma unroll
      for (int r = 0; r < 4; ++r) {
        int o = wm * 64 + mi * 16 + kg * 4 + r;
#pragma unroll
        for (int ni = 0; ni < 4; ++ni) {
          int n = wn * 64 + ni * 16 + rl;
          Cb[(long)o * 4096 + n] = f2bf(acc[mi][ni][r]);
        }
      }
    }
  }
}

// ---------------- GEMM2: lin = Wf[b] @ qT^T + b_out, fused GN partial stats ---
__global__ __launch_bounds__(256) void gemm_lin(
    const short* __restrict__ A, const short* __restrict__ Bt,
    short* __restrict__ C, const float* __restrict__ bias,
    float* __restrict__ st2) {
  __shared__ short lA[8192];
  __shared__ short lB[8192];
  int b = blockIdx.z;
  int mt = blockIdx.y * 128, nt = blockIdx.x * 128;
  int tid = threadIdx.x;
  int lane = tid & 63;
  int wm = tid >> 7, wn = (tid >> 6) & 1;
  int rl = lane & 15, kg = lane >> 4;
  const short* Ab = A + (long)b * 65536 + (long)mt * 256;
  const short* Bb = Bt + ((long)b * 4096 + nt) * 256;

  f32x4 acc[4][4];
#pragma unroll
  for (int i = 0; i < 4; ++i)
#pragma unroll
    for (int j = 0; j < 4; ++j) acc[i][j] = (f32x4){0.f, 0.f, 0.f, 0.f};

  for (int k0 = 0; k0 < 256; k0 += 64) {
#pragma unroll
    for (int is = 0; is < 4; ++is) {
      int s = is * 256 + tid;
      int row = s >> 3, kcp = s & 7;
      int kcl = kcp ^ (row & 7);
      gld16(Ab + (long)row * 256 + k0 + kcl * 8, &lA[(is * 256 + (tid & ~63)) * 8]);
      gld16(Bb + (long)row * 256 + k0 + kcl * 8, &lB[(is * 256 + (tid & ~63)) * 8]);
    }
    asm volatile("s_waitcnt vmcnt(0)" ::: "memory");
    __syncthreads();
#pragma unroll
    for (int kw = 0; kw < 2; ++kw) {
      int kc = kw * 4 + kg;
      s8v av[4], bv[4];
#pragma unroll
      for (int mi = 0; mi < 4; ++mi) {
        int row = wm * 64 + mi * 16 + rl;
        av[mi] = *(const s8v*)&lA[row * 64 + ((kc ^ (row & 7)) << 3)];
      }
#pragma unroll
      for (int ni = 0; ni < 4; ++ni) {
        int row = wn * 64 + ni * 16 + rl;
        bv[ni] = *(const s8v*)&lB[row * 64 + ((kc ^ (row & 7)) << 3)];
      }
#pragma unroll
      for (int mi = 0; mi < 4; ++mi)
#pragma unroll
        for (int ni = 0; ni < 4; ++ni)
          acc[mi][ni] = __builtin_amdgcn_mfma_f32_16x16x32_bf16(
              av[mi], bv[ni], acc[mi][ni], 0, 0, 0);
    }
    __syncthreads();
  }

  short* Cb = C + ((long)b * 256 + mt) * 4096 + nt;
  float s1[4] = {0.f, 0.f, 0.f, 0.f};
  float s2[4] = {0.f, 0.f, 0.f, 0.f};
#pragma unroll
  for (int mi = 0; mi < 4; ++mi) {
#pragma unroll
    for (int r = 0; r < 4; ++r) {
      int o = wm * 64 + mi * 16 + kg * 4 + r;
      float bv = bias[mt + o];
#pragma unroll
      for (int ni = 0; ni < 4; ++ni) {
        int n = wn * 64 + ni * 16 + rl;
        short h = f2bf(acc[mi][ni][r] + bv);
        Cb[(long)o * 4096 + n] = h;
        float q = bf2f(h);
        s1[mi] += q;
        s2[mi] += q * q;
      }
    }
  }
#pragma unroll
  for (int mi = 0; mi < 4; ++mi) {
#pragma unroll
    for (int off = 1; off <= 16; off <<= 1) {
      s1[mi] += __shfl_xor(s1[mi], off);
      s2[mi] += __shfl_xor(s2[mi], off);
    }
    if (rl == 0 && (kg & 1) == 0) {
      int g = (mt >> 3) + wm * 8 + mi * 2 + (kg >> 1);
      atomicAdd(&st2[(b * 32 + g) * 2], s1[mi]);
      atomicAdd(&st2[(b * 32 + g) * 2 + 1], s2[mi]);
    }
  }
}

// ---------------- ctx via MFMA: ctx[d][e] = sum_n exp(k[d][n]) v[e][n] --------
__global__ __launch_bounds__(256) void ctx_mfma(
    const short* __restrict__ kv, float* __restrict__ ctxp, float* __restrict__ sp) {
  int split = blockIdx.x;
  int h = blockIdx.y, b = blockIdx.z;
  int tid = threadIdx.x;
  int w = tid >> 6, l = tid & 63;
  const short* kb = kv + ((long)(b * 512) + h * 32) * 4096;
  const short* vb = kb + (long)256 * 4096;
  int rl = l & 15, kg = l >> 4;
  int n_base = split * 1024 + w * 256;

  f32x4 acc[2][2];
#pragma unroll
  for (int i = 0; i < 2; ++i)
#pragma unroll
    for (int j = 0; j < 2; ++j) acc[i][j] = (f32x4){0.f, 0.f, 0.f, 0.f};
  float s_part0 = 0.f, s_part1 = 0.f;

#pragma unroll 2
  for (int it = 0; it < 8; ++it) {
    int n0 = n_base + it * 32 + kg * 8;
    s8v a0, a1, b0, b1;
    {
      s8v kr = *(const s8v*)&kb[(long)rl * 4096 + n0];
#pragma unroll
      for (int j = 0; j < 8; ++j) {
        float f = __expf(bf2f(kr[j]));
        s_part0 += f;
        a0[j] = f2bf_t(f);
      }
    }
    {
      s8v kr = *(const s8v*)&kb[(long)(16 + rl) * 4096 + n0];
#pragma unroll
      for (int j = 0; j < 8; ++j) {
        float f = __expf(bf2f(kr[j]));
        s_part1 += f;
        a1[j] = f2bf_t(f);
      }
    }
    b0 = *(const s8v*)&vb[(long)rl * 4096 + n0];
    b1 = *(const s8v*)&vb[(long)(16 + rl) * 4096 + n0];
    acc[0][0] = __builtin_amdgcn_mfma_f32_16x16x32_bf16(a0, b0, acc[0][0], 0, 0, 0);
    acc[0][1] = __builtin_amdgcn_mfma_f32_16x16x32_bf16(a0, b1, acc[0][1], 0, 0, 0);
    acc[1][0] = __builtin_amdgcn_mfma_f32_16x16x32_bf16(a1, b0, acc[1][0], 0, 0, 0);
    acc[1][1] = __builtin_amdgcn_mfma_f32_16x16x32_bf16(a1, b1, acc[1][1], 0, 0, 0);
  }
  s_part0 += __shfl_xor(s_part0, 16); s_part0 += __shfl_xor(s_part0, 32);
  s_part1 += __shfl_xor(s_part1, 16); s_part1 += __shfl_xor(s_part1, 32);

  __shared__ float lctx[4][1024];
  __shared__ float lsum[4][32];
#pragma unroll
  for (int di = 0; di < 2; ++di)
#pragma unroll
    for (int ei = 0; ei < 2; ++ei)
#pragma unroll
      for (int r = 0; r < 4; ++r) {
        int row = di * 16 + kg * 4 + r;
        int col = ei * 16 + rl;
        lctx[w][row * 32 + col] = acc[di][ei][r];
      }
  if (kg == 0) { lsum[w][rl] = s_part0; lsum[w][16 + rl] = s_part1; }
  __syncthreads();
  long base = (long)(b * 8 + h) * 4 + split;
#pragma unroll
  for (int i = 0; i < 4; ++i) {
    int id = tid + i * 256;
    ctxp[base * 1024 + id] = lctx[0][id] + lctx[1][id] + lctx[2][id] + lctx[3][id];
  }
  if (tid < 32)
    sp[base * 32 + tid] = lsum[0][tid] + lsum[1][tid] + lsum[2][tid] + lsum[3][tid];
}

// ---------------- Wf[b][o][h*32+d] = sum_e w_out[o][h*32+e] * ctx[d][e]/s_d ---
__global__ __launch_bounds__(256) void make_wf(
    const float* __restrict__ ctxp, const float* __restrict__ sp,
    const float* __restrict__ w_out, short* __restrict__ wf) {
  int h = blockIdx.x, b = blockIdx.y;
  __shared__ float c[32][33];
  __shared__ float inv_s[32];
  __shared__ float wv[256][33];
  int t = threadIdx.x;
  long base = (long)(b * 8 + h) * 4;
#pragma unroll
  for (int i = 0; i < 4; ++i) {
    int id = t + i * 256;
    float v = ctxp[base * 1024 + id] + ctxp[(base + 1) * 1024 + id] +
              ctxp[(base + 2) * 1024 + id] + ctxp[(base + 3) * 1024 + id];
    c[id >> 5][id & 31] = v;
  }
  if (t < 32) {
    float sv = sp[base * 32 + t] + sp[(base + 1) * 32 + t] +
               sp[(base + 2) * 32 + t] + sp[(base + 3) * 32 + t];
    inv_s[t] = 1.f / sv;
  }
#pragma unroll
  for (int r = 0; r < 32; ++r) {
    int row = r * 8 + (t >> 5);
    wv[row][t & 31] = w_out[row * 256 + h * 32 + (t & 31)];
  }
  __syncthreads();
  float wr[32];
#pragma unroll
  for (int e = 0; e < 32; ++e) wr[e] = wv[t][e];
  float tmp[32];
#pragma unroll
  for (int dd = 0; dd < 32; ++dd) {
    float sum = 0.f;
#pragma unroll
    for (int e = 0; e < 32; ++e) sum += wr[e] * c[dd][e];
    tmp[dd] = sum * inv_s[dd];
  }
  short* dst = wf + ((long)b * 256 + t) * 256 + h * 32;
#pragma unroll
  for (int c8 = 0; c8 < 4; ++c8) {
    s8v o;
#pragma unroll
    for (int e = 0; e < 8; ++e) o[e] = f2bf(tmp[c8 * 8 + e]);
    *(s8v*)&dst[c8 * 8] = o;
  }
}

// ---------------- normalize + affine + residual --------------------------------
__global__ __launch_bounds__(256) void final_out(
    const short* __restrict__ lin, const float* __restrict__ x,
    const float2* __restrict__ st2, const float* __restrict__ gamma,
    const float* __restrict__ beta, float* __restrict__ out) {
  long id = (long)blockIdx.x * 256 + threadIdx.x;
  long e0 = id * 8;
  int b = (int)(e0 >> 20);
  int rem = (int)(e0 & 1048575);
  int c = rem >> 12;
  float2 st = st2[b * 32 + (c >> 3)];
  float mean = st.x * (1.f / 32768.f);
  float inv = rsqrtf(st.y * (1.f / 32768.f) - mean * mean + 1e-6f);
  float ga = gamma[c] * inv;
  float be = beta[c] - mean * ga;
  s8v l8 = *(const s8v*)&lin[e0];
  float4 x0 = *(const float4*)&x[e0];
  float4 x1 = *(const float4*)&x[e0 + 4];
  float4 o0, o1;
  o0.x = bf2f(l8[0]) * ga + be + x0.x;
  o0.y = bf2f(l8[1]) * ga + be + x0.y;
  o0.z = bf2f(l8[2]) * ga + be + x0.z;
  o0.w = bf2f(l8[3]) * ga + be + x0.w;
  o1.x = bf2f(l8[4]) * ga + be + x1.x;
  o1.y = bf2f(l8[5]) * ga + be + x1.y;
  o1.z = bf2f(l8[6]) * ga + be + x1.z;
  o1.w = bf2f(l8[7]) * ga + be + x1.w;
  *(float4*)&out[e0] = o0;
  *(float4*)&out[e0 + 4] = o1;
}

extern "C" void kernel_launch(void* const* d_in, const int* in_sizes, int n_in,
                              void* d_out, int out_size, void* d_ws, size_t ws_size,
                              hipStream_t stream) {
  const float* x     = (const float*)d_in[0];
  const float* w_qkv = (const float*)d_in[1];
  const float* w_out = (const float*)d_in[2];
  const float* b_out = (const float*)d_in[3];
  const float* gamma = (const float*)d_in[4];
  const float* beta  = (const float*)d_in[5];
  float* out = (float*)d_out;

  short* xt   = (short*)d_ws;              // 16*4096*256 shorts (32MB)
  short* qT   = xt + 16777216;             // 32MB
  short* kvb  = qT + 16777216;             // 16*512*4096 shorts (64MB)
  short* lin  = kvb + 33554432;            // 32MB
  short* wqb  = lin + 16777216;            // 196,608 shorts
  short* wfb  = wqb + 196608;              // 1M shorts
  float* ctxp = (float*)(wfb + 1048576);   // 524,288 floats
  float* sp   = ctxp + 524288;             // 16,384 floats
  float* st2  = sp + 16384;                // 1,024 floats (atomically accumulated)

  prep<<<dim3(64, 4, 17), 256, 0, stream>>>(x, xt, w_qkv, wqb, st2);
  gemm_qkv<<<dim3(32, 6, 16), 256, 0, stream>>>(wqb, xt, kvb, qT);
  ctx_mfma<<<dim3(4, 8, 16), 256, 0, stream>>>(kvb, ctxp, sp);
  make_wf<<<dim3(8, 16), 256, 0, stream>>>(ctxp, sp, w_out, wfb);
  gemm_lin<<<dim3(32, 2, 16), 256, 0, stream>>>(wfb, qT, lin, b_out, st2);
  final_out<<<8192, 256, 0, stream>>>(lin, x, (const float2*)st2, gamma, beta, out);
}